// Round 1
// baseline (89.111 us; speedup 1.0000x reference)
//
#include <hip/hip_runtime.h>

namespace {

constexpr int IMG = 512;
constexpr int S = 4;                    // output rows per wave
constexpr int NSTRIPS = IMG / S;        // 128
constexpr int NWAVES = 32 * NSTRIPS;    // 4096
constexpr int NBLK = NWAVES / 2;        // 2048 blocks of 2 waves
constexpr float THR = 50.0f / 255.0f;

// Final loss is linear in the 5 raw sums; pre-weight per wave.
constexpr double N_PIX = 32.0 * 512.0 * 512.0;
constexpr double N_L1  = 32.0 * 256.0 * 256.0;
constexpr double N_L2  = 32.0 * 128.0 * 128.0;
constexpr double N_L3  = 32.0 * 64.0 * 64.0;
constexpr double C_REC = 1.0 / N_PIX;
constexpr double C_REG = 2.0 / N_PIX;
constexpr double C_W1  = 0.05 / (9.0 * N_L1);
constexpr double C_W2  = 0.05 / (6.0 * N_L2);
constexpr double C_W3  = 0.05 / (3.0 * N_L3);

struct F4 { float v[4]; };
struct F8 { float v[8]; };
struct Row { F8 g; float gl, gr; };     // 8 cols + pre-shuffled zero-pad halos

// Horizontal resize blend: 4 phase values (cols j=4L..4L+3) -> 8 upsampled cols.
// jax.image.resize 'linear' 256->512: even g=2j: 0.25*in[j-1]+0.75*in[j];
// odd g=2j+1: 0.75*in[j]+0.25*in[j+1]; index-clamped (bit-exact).
__device__ __forceinline__ F8 hblend(const F4& p, int lane) {
  float left  = __shfl_up(p.v[3], 1);
  float right = __shfl_down(p.v[0], 1);
  if (lane == 0)  left  = p.v[0];
  if (lane == 63) right = p.v[3];
  F8 h;
  h.v[0] = 0.25f*left   + 0.75f*p.v[0];
  h.v[1] = 0.75f*p.v[0] + 0.25f*p.v[1];
  h.v[2] = 0.25f*p.v[0] + 0.75f*p.v[1];
  h.v[3] = 0.75f*p.v[1] + 0.25f*p.v[2];
  h.v[4] = 0.25f*p.v[1] + 0.75f*p.v[2];
  h.v[5] = 0.75f*p.v[2] + 0.25f*p.v[3];
  h.v[6] = 0.25f*p.v[2] + 0.75f*p.v[3];
  h.v[7] = 0.75f*p.v[3] + 0.25f*right;
  return h;
}

// Vertical resize blend -> one g1 row, with conv zero-pad halos pre-shuffled.
__device__ __forceinline__ Row vblend(const F8& a, const F8& b, float wa, float wb, int lane) {
  Row r;
#pragma unroll
  for (int c = 0; c < 8; ++c) r.g.v[c] = wa*a.v[c] + wb*b.v[c];
  const float gl = __shfl_up(r.g.v[7], 1);
  const float gr = __shfl_down(r.g.v[0], 1);
  r.gl = (lane == 0)  ? 0.0f : gl;
  r.gr = (lane == 63) ? 0.0f : gr;
  return r;
}

__device__ __forceinline__ void conv_acc(const Row& r, const float* wk3, F8& acc) {
#pragma unroll
  for (int c = 0; c < 8; ++c) {
    const float gm1 = (c == 0) ? r.gl : r.g.v[c-1];
    const float gp1 = (c == 7) ? r.gr : r.g.v[c+1];
    acc.v[c] += wk3[0]*gm1 + wk3[1]*r.g.v[c] + wk3[2]*gp1;
  }
}

__device__ __forceinline__ F8 conv3(const Row& r0, const Row& r1, const Row& r2,
                                    const float* wk) {
  F8 o;
#pragma unroll
  for (int c = 0; c < 8; ++c) o.v[c] = 0.0f;
  conv_acc(r0, wk + 0, o);
  conv_acc(r1, wk + 3, o);
  conv_acc(r2, wk + 6, o);
#pragma unroll
  for (int c = 0; c < 8; ++c) o.v[c] = fminf(fmaxf(o.v[c], 0.0f), 1.0f);
  return o;
}

__device__ __forceinline__ F4 haarL1(const F8& e, const F8& o, float thr, float& acc) {
  F4 ll;
#pragma unroll
  for (int c = 0; c < 4; ++c) {
    const float a = e.v[2*c], b = e.v[2*c+1], cc = o.v[2*c], d = o.v[2*c+1];
    ll.v[c] = (a + b + cc + d) * 0.5f;
    const float lh = (a - b + cc - d) * 0.5f;
    const float hl = (a + b - cc - d) * 0.5f;
    const float hh = (a - b - cc + d) * 0.5f;
    acc += fminf(fabsf(lh), thr) + fminf(fabsf(hl), thr) + fminf(fabsf(hh), thr);
  }
  return ll;
}

__device__ __forceinline__ float haar1pair(float a, float b, float cc, float d,
                                           float thr, float& acc) {
  const float lh = (a - b + cc - d) * 0.5f;
  const float hl = (a + b - cc - d) * 0.5f;
  const float hh = (a - b - cc + d) * 0.5f;
  acc += fminf(fabsf(lh), thr) + fminf(fabsf(hl), thr) + fminf(fabsf(hh), thr);
  return (a + b + cc + d) * 0.5f;
}

// 2 waves/block; wave widx handles strip (blockIdx*2+widx) & 127 of image gwid>>7.
// Even strip computes Haar L1+L2; its single ll2 row goes to LDS; odd strip's
// wave combines it with its own ll2 row for the L3 terms.
__global__ __launch_bounds__(128, 3) void n2n_wavelet_kernel(
    const float* __restrict__ noisy,
    const float* __restrict__ weight,
    double* __restrict__ partial) {
  __shared__ float ll2sh[128];
  const int t = threadIdx.x;
  const int lane = t & 63;
  const int widx = t >> 6;
  const int gwid = blockIdx.x * 2 + widx;
  const int strip = gwid & (NSTRIPS - 1);
  const int b = gwid >> 7;
  const float* base = noisy + (size_t)b * IMG * IMG + lane * 8;

  const int y0 = strip * S;
  const int k0 = y0 >> 1;                 // phase-row index of first pair
  const bool lastStrip = (strip == NSTRIPS - 1);

  // weight -> SGPRs (uniform), frees VGPRs; VOP3 FMA reads 1 SGPR operand.
  float wk[9];
#pragma unroll
  for (int i = 0; i < 9; ++i)
    wk[i] = __uint_as_float(__builtin_amdgcn_readfirstlane(__float_as_uint(weight[i])));

  // ---- Phase rows k0-1 .. k0+2 (clamped): load + extract + hblend ----
  F8 h0[4], h3[4];
#pragma unroll
  for (int i = 0; i < 4; ++i) {
    int r = k0 - 1 + i;
    r = r < 0 ? 0 : (r > 255 ? 255 : r);
    const float* pe = base + (size_t)(2 * r) * IMG;     // even image row (p0)
    const float* po = pe + IMG;                         // odd image row (p3)
    const float4 e0 = *(const float4*)pe;
    const float4 e1 = *(const float4*)(pe + 4);
    const float4 o0 = *(const float4*)po;
    const float4 o1 = *(const float4*)(po + 4);
    F4 e, o;
    e.v[0] = e0.x; e.v[1] = e0.z; e.v[2] = e1.x; e.v[3] = e1.z;
    o.v[0] = o0.y; o.v[1] = o0.w; o.v[2] = o1.y; o.v[3] = o1.w;
    h0[i] = hblend(e, lane);
    h3[i] = hblend(o, lane);
  }

  float rec = 0.f, rgg = 0.f, w1a = 0.f, w2a = 0.f, w3a = 0.f;
  const float thr1 = THR * 0.25f, thr2 = THR * 0.5f;

  // ---- g1 prologue rows y0-1 (odd), y0 (even) ----
  Row g1m, g1c;
  if (y0 == 0) {                                  // SAME conv zero-pad row -1
#pragma unroll
    for (int c = 0; c < 8; ++c) g1m.g.v[c] = 0.f;
    g1m.gl = 0.f; g1m.gr = 0.f;
  } else {
    g1m = vblend(h0[0], h0[1], 0.75f, 0.25f, lane);
  }
  g1c = vblend(h0[0], h0[1], 0.25f, 0.75f, lane);

  F4 ll1Prev;
  float ll20 = 0.f, ll21 = 0.f;

#pragma unroll
  for (int p = 0; p < 2; ++p) {
    const Row g1p = vblend(h0[p + 1], h0[p + 2], 0.75f, 0.25f, lane);  // g1[2k+1]

    // out row 2k (even)
    const F8 outE = conv3(g1m, g1c, g1p, wk);
#pragma unroll
    for (int c = 0; c < 8; ++c) {
      const float g2 = 0.25f * h3[p].v[c] + 0.75f * h3[p + 1].v[c];
      float d = outE.v[c] - g2;        rec += d*d;
      d = outE.v[c] - g1c.g.v[c];      rgg += d*d;
    }

    Row g1q = vblend(h0[p + 1], h0[p + 2], 0.25f, 0.75f, lane);        // g1[2k+2]
    if (lastStrip && p == 1) {                                         // g1[512]=0
#pragma unroll
      for (int c = 0; c < 8; ++c) g1q.g.v[c] = 0.f;
      g1q.gl = 0.f; g1q.gr = 0.f;
    }

    // out row 2k+1 (odd)
    const F8 outO = conv3(g1c, g1p, g1q, wk);
#pragma unroll
    for (int c = 0; c < 8; ++c) {
      const float g2 = 0.75f * h3[p + 1].v[c] + 0.25f * h3[p + 2].v[c];
      float d = outO.v[c] - g2;        rec += d*d;
      d = outO.v[c] - g1p.g.v[c];      rgg += d*d;
    }

    // Haar level 1 (rows 2k,2k+1; col pairs lane-local)
    const F4 ll1 = haarL1(outE, outO, thr1, w1a);
    if (p == 0) {
      ll1Prev = ll1;
    } else {
      ll20 = haar1pair(ll1Prev.v[0], ll1Prev.v[1], ll1.v[0], ll1.v[1], thr2, w2a);
      ll21 = haar1pair(ll1Prev.v[2], ll1Prev.v[3], ll1.v[2], ll1.v[3], thr2, w2a);
    }

    g1m = g1p; g1c = g1q;
  }

  // ---- Haar level 3: even strip's ll2 row (a,b) + odd strip's (c,d) ----
  if (widx == 0) {
    ll2sh[2 * lane]     = ll20;
    ll2sh[2 * lane + 1] = ll21;
  }
  __syncthreads();
  if (widx == 1) {
    const float a  = ll2sh[2 * lane];
    const float bb = ll2sh[2 * lane + 1];
    const float lh = (a - bb + ll20 - ll21) * 0.5f;
    const float hl = (a + bb - ll20 - ll21) * 0.5f;
    const float hh = (a - bb - ll20 + ll21) * 0.5f;
    w3a += fminf(fabsf(lh), THR) + fminf(fabsf(hl), THR) + fminf(fabsf(hh), THR);
  }

  // ---- Wave reduce -> one pre-weighted double per wave, plain store ----
  float vals[5] = {rec, rgg, w1a, w2a, w3a};
#pragma unroll
  for (int v = 0; v < 5; ++v) {
#pragma unroll
    for (int off = 32; off > 0; off >>= 1) vals[v] += __shfl_down(vals[v], off);
  }
  if (lane == 0) {
    partial[gwid] = C_REC*(double)vals[0] + C_REG*(double)vals[1]
                  + C_W1*(double)vals[2] + C_W2*(double)vals[3] + C_W3*(double)vals[4];
  }
}

__global__ __launch_bounds__(256) void finalize_kernel(
    const double* __restrict__ partial, float* __restrict__ out) {
  __shared__ double sRed[4];
  const int t = threadIdx.x;
  double s = 0.0;
#pragma unroll
  for (int i = 0; i < NWAVES / 256; ++i) s += partial[i * 256 + t];
#pragma unroll
  for (int off = 32; off > 0; off >>= 1) s += __shfl_down(s, off);
  if ((t & 63) == 0) sRed[t >> 6] = s;
  __syncthreads();
  if (t == 0) out[0] = (float)(sRed[0] + sRed[1] + sRed[2] + sRed[3]);
}

}  // namespace

extern "C" void kernel_launch(void* const* d_in, const int* in_sizes, int n_in,
                              void* d_out, int out_size, void* d_ws, size_t ws_size,
                              hipStream_t stream) {
  const float* noisy  = (const float*)d_in[0];
  const float* weight = (const float*)d_in[1];
  double* partial = (double*)d_ws;   // NWAVES doubles = 32 KB
  float* out = (float*)d_out;

  hipLaunchKernelGGL(n2n_wavelet_kernel, dim3(NBLK), dim3(128), 0, stream,
                     noisy, weight, partial);
  hipLaunchKernelGGL(finalize_kernel, dim3(1), dim3(256), 0, stream, partial, out);
}

// Round 2
// 83.800 us; speedup vs baseline: 1.0634x; 1.0634x over previous
//
#include <hip/hip_runtime.h>

namespace {

constexpr int IMG = 512;
constexpr int S = 8;                    // output rows per wave
constexpr int NSTRIPS = IMG / S;        // 64
constexpr int NWAVES = 32 * NSTRIPS;    // 2048
constexpr int NBLK = NWAVES / 4;        // 512 blocks of 4 waves
constexpr float THR = 50.0f / 255.0f;

// Final loss is linear in the 5 raw sums; pre-weight per wave.
constexpr double N_PIX = 32.0 * 512.0 * 512.0;
constexpr double N_L1  = 32.0 * 256.0 * 256.0;
constexpr double N_L2  = 32.0 * 128.0 * 128.0;
constexpr double N_L3  = 32.0 * 64.0 * 64.0;
constexpr double C_REC = 1.0 / N_PIX;
constexpr double C_REG = 2.0 / N_PIX;
constexpr double C_W1  = 0.05 / (9.0 * N_L1);
constexpr double C_W2  = 0.05 / (6.0 * N_L2);
constexpr double C_W3  = 0.05 / (3.0 * N_L3);

struct F4 { float v[4]; };
struct F8 { float v[8]; };
struct Row { F8 g; float gl, gr; };     // 8 cols + pre-shuffled zero-pad halos

// Horizontal resize blend: 4 phase values (cols j=4L..4L+3) -> 8 upsampled cols.
// jax.image.resize 'linear' 256->512: even g=2j: 0.25*in[j-1]+0.75*in[j];
// odd g=2j+1: 0.75*in[j]+0.25*in[j+1]; index-clamped (bit-exact).
__device__ __forceinline__ F8 hblend(const F4& p, int lane) {
  float left  = __shfl_up(p.v[3], 1);
  float right = __shfl_down(p.v[0], 1);
  if (lane == 0)  left  = p.v[0];
  if (lane == 63) right = p.v[3];
  F8 h;
  h.v[0] = 0.25f*left   + 0.75f*p.v[0];
  h.v[1] = 0.75f*p.v[0] + 0.25f*p.v[1];
  h.v[2] = 0.25f*p.v[0] + 0.75f*p.v[1];
  h.v[3] = 0.75f*p.v[1] + 0.25f*p.v[2];
  h.v[4] = 0.25f*p.v[1] + 0.75f*p.v[2];
  h.v[5] = 0.75f*p.v[2] + 0.25f*p.v[3];
  h.v[6] = 0.25f*p.v[2] + 0.75f*p.v[3];
  h.v[7] = 0.75f*p.v[3] + 0.25f*right;
  return h;
}

// Load one phase-row pair (even image row 2r = p0 phase, odd row 2r+1 = p3
// phase), extract checkerboard phases, horizontal-blend both.
__device__ __forceinline__ void loadPair(const float* __restrict__ base, int r,
                                         F8& h0o, F8& h3o, int lane) {
  const float* pe = base + (size_t)(2 * r) * IMG;
  const float* po = pe + IMG;
  const float4 e0 = *(const float4*)pe;
  const float4 e1 = *(const float4*)(pe + 4);
  const float4 o0 = *(const float4*)po;
  const float4 o1 = *(const float4*)(po + 4);
  F4 e, o;
  e.v[0] = e0.x; e.v[1] = e0.z; e.v[2] = e1.x; e.v[3] = e1.z;
  o.v[0] = o0.y; o.v[1] = o0.w; o.v[2] = o1.y; o.v[3] = o1.w;
  h0o = hblend(e, lane);
  h3o = hblend(o, lane);
}

// Vertical resize blend -> one g1 row, with conv zero-pad halos pre-shuffled.
__device__ __forceinline__ Row vblend(const F8& a, const F8& b, float wa, float wb, int lane) {
  Row r;
#pragma unroll
  for (int c = 0; c < 8; ++c) r.g.v[c] = wa*a.v[c] + wb*b.v[c];
  const float gl = __shfl_up(r.g.v[7], 1);
  const float gr = __shfl_down(r.g.v[0], 1);
  r.gl = (lane == 0)  ? 0.0f : gl;
  r.gr = (lane == 63) ? 0.0f : gr;
  return r;
}

__device__ __forceinline__ void conv_acc(const Row& r, const float* wk3, F8& acc) {
#pragma unroll
  for (int c = 0; c < 8; ++c) {
    const float gm1 = (c == 0) ? r.gl : r.g.v[c-1];
    const float gp1 = (c == 7) ? r.gr : r.g.v[c+1];
    acc.v[c] += wk3[0]*gm1 + wk3[1]*r.g.v[c] + wk3[2]*gp1;
  }
}

__device__ __forceinline__ F8 conv3(const Row& r0, const Row& r1, const Row& r2,
                                    const float* wk) {
  F8 o;
#pragma unroll
  for (int c = 0; c < 8; ++c) o.v[c] = 0.0f;
  conv_acc(r0, wk + 0, o);
  conv_acc(r1, wk + 3, o);
  conv_acc(r2, wk + 6, o);
#pragma unroll
  for (int c = 0; c < 8; ++c) o.v[c] = fminf(fmaxf(o.v[c], 0.0f), 1.0f);
  return o;
}

__device__ __forceinline__ F4 haarL1(const F8& e, const F8& o, float thr, float& acc) {
  F4 ll;
#pragma unroll
  for (int c = 0; c < 4; ++c) {
    const float a = e.v[2*c], b = e.v[2*c+1], cc = o.v[2*c], d = o.v[2*c+1];
    ll.v[c] = (a + b + cc + d) * 0.5f;
    const float lh = (a - b + cc - d) * 0.5f;
    const float hl = (a + b - cc - d) * 0.5f;
    const float hh = (a - b - cc + d) * 0.5f;
    acc += fminf(fabsf(lh), thr) + fminf(fabsf(hl), thr) + fminf(fabsf(hh), thr);
  }
  return ll;
}

__device__ __forceinline__ float haar1pair(float a, float b, float cc, float d,
                                           float thr, float& acc) {
  const float lh = (a - b + cc - d) * 0.5f;
  const float hl = (a + b - cc - d) * 0.5f;
  const float hh = (a - b - cc + d) * 0.5f;
  acc += fminf(fabsf(lh), thr) + fminf(fabsf(hl), thr) + fminf(fabsf(hh), thr);
  return (a + b + cc + d) * 0.5f;
}

// LDS halo sharing: slot holds one pair's h0 (even phase) + h3 (odd phase)
// blends for all 64 lanes, split into two float4 halves each.
// sh[slot][phase][half][lane] — writes/reads are lane*16B contiguous b128.
__device__ __forceinline__ void storeSh(float4 (&s)[2][2][64], const F8& a,
                                        const F8& b, int lane) {
  s[0][0][lane] = make_float4(a.v[0], a.v[1], a.v[2], a.v[3]);
  s[0][1][lane] = make_float4(a.v[4], a.v[5], a.v[6], a.v[7]);
  s[1][0][lane] = make_float4(b.v[0], b.v[1], b.v[2], b.v[3]);
  s[1][1][lane] = make_float4(b.v[4], b.v[5], b.v[6], b.v[7]);
}

__device__ __forceinline__ void loadSh(const float4 (&s)[2][2][64], F8& a,
                                       F8& b, int lane) {
  const float4 a0 = s[0][0][lane], a1 = s[0][1][lane];
  const float4 b0 = s[1][0][lane], b1 = s[1][1][lane];
  a.v[0] = a0.x; a.v[1] = a0.y; a.v[2] = a0.z; a.v[3] = a0.w;
  a.v[4] = a1.x; a.v[5] = a1.y; a.v[6] = a1.z; a.v[7] = a1.w;
  b.v[0] = b0.x; b.v[1] = b0.y; b.v[2] = b0.z; b.v[3] = b0.w;
  b.v[4] = b1.x; b.v[5] = b1.y; b.v[6] = b1.z; b.v[7] = b1.w;
}

// 4 waves/block = 4 consecutive strips of one image. Each wave loads its 4
// core phase-row pairs (k0..k0+3); halo pairs (k0-1, k0+4) are the neighbor
// waves' last/first core pairs, shared via LDS (bit-exact: same lane->col
// mapping in every wave). Block-edge waves direct-load their outside halo.
// Global pair-loads per block: 18 vs 24 unshared (-27% traffic).
__global__ __launch_bounds__(256, 2) void n2n_wavelet_kernel(
    const float* __restrict__ noisy,
    const float* __restrict__ weight,
    double* __restrict__ partial) {
  __shared__ float4 sh[8][2][2][64];    // 16 KB
  const int t = threadIdx.x;
  const int lane = t & 63;
  const int widx = t >> 6;
  const int gwid = blockIdx.x * 4 + widx;
  const int strip = gwid & (NSTRIPS - 1);
  const int b = gwid >> 6;
  const float* base = noisy + (size_t)b * IMG * IMG + lane * 8;

  const int y0 = strip * S;
  const int k0 = y0 >> 1;                 // phase-row index of first pair
  const bool lastStrip = (strip == NSTRIPS - 1);

  // weight -> SGPRs (uniform); VOP3 FMA reads 1 SGPR operand.
  float wk[9];
#pragma unroll
  for (int i = 0; i < 9; ++i)
    wk[i] = __uint_as_float(__builtin_amdgcn_readfirstlane(__float_as_uint(weight[i])));

  // ---- Core pairs: window idx 1..4 = pairs k0..k0+3 (never clamps) ----
  F8 h0[6], h3[6];
#pragma unroll
  for (int wi = 1; wi <= 4; ++wi)
    loadPair(base, k0 + (wi - 1), h0[wi], h3[wi], lane);

  // Block-edge halos loaded directly (wave-uniform branches).
  if (widx == 0) {
    int r = k0 - 1; r = r < 0 ? 0 : r;
    loadPair(base, r, h0[0], h3[0], lane);
  }
  if (widx == 3) {
    int r = k0 + 4; r = r > 255 ? 255 : r;
    loadPair(base, r, h0[5], h3[5], lane);
  }

  // Publish first/last core pair; fetch halos from neighbors.
  storeSh(sh[2 * widx],     h0[1], h3[1], lane);
  storeSh(sh[2 * widx + 1], h0[4], h3[4], lane);
  __syncthreads();
  if (widx > 0) loadSh(sh[2 * widx - 1], h0[0], h3[0], lane);
  if (widx < 3) loadSh(sh[2 * widx + 2], h0[5], h3[5], lane);

  float rec = 0.f, rgg = 0.f, w1a = 0.f, w2a = 0.f, w3a = 0.f;
  const float thr1 = THR * 0.25f, thr2 = THR * 0.5f;

  // ---- g1 prologue rows y0-1 (odd), y0 (even) ----
  Row g1m, g1c;
  if (y0 == 0) {                                  // SAME conv zero-pad row -1
#pragma unroll
    for (int c = 0; c < 8; ++c) g1m.g.v[c] = 0.f;
    g1m.gl = 0.f; g1m.gr = 0.f;
  } else {
    g1m = vblend(h0[0], h0[1], 0.75f, 0.25f, lane);
  }
  g1c = vblend(h0[0], h0[1], 0.25f, 0.75f, lane);

  F4 ll1Prev;
  float ll2Prev0 = 0.f, ll2Prev1 = 0.f;

#pragma unroll
  for (int p = 0; p < 4; ++p) {
    const Row g1p = vblend(h0[p + 1], h0[p + 2], 0.75f, 0.25f, lane);  // g1[2k+1]

    // out row 2k (even)
    const F8 outE = conv3(g1m, g1c, g1p, wk);
#pragma unroll
    for (int c = 0; c < 8; ++c) {
      const float g2 = 0.25f * h3[p].v[c] + 0.75f * h3[p + 1].v[c];
      float d = outE.v[c] - g2;        rec += d*d;
      d = outE.v[c] - g1c.g.v[c];      rgg += d*d;
    }

    Row g1q = vblend(h0[p + 1], h0[p + 2], 0.25f, 0.75f, lane);        // g1[2k+2]
    if (lastStrip && p == 3) {                                         // g1[512]=0
#pragma unroll
      for (int c = 0; c < 8; ++c) g1q.g.v[c] = 0.f;
      g1q.gl = 0.f; g1q.gr = 0.f;
    }

    // out row 2k+1 (odd)
    const F8 outO = conv3(g1c, g1p, g1q, wk);
#pragma unroll
    for (int c = 0; c < 8; ++c) {
      const float g2 = 0.75f * h3[p + 1].v[c] + 0.25f * h3[p + 2].v[c];
      float d = outO.v[c] - g2;        rec += d*d;
      d = outO.v[c] - g1p.g.v[c];      rgg += d*d;
    }

    // Haar level 1 (rows 2k,2k+1; col pairs lane-local)
    const F4 ll1 = haarL1(outE, outO, thr1, w1a);
    if ((p & 1) == 0) {
      ll1Prev = ll1;
    } else {
      const float ll20 = haar1pair(ll1Prev.v[0], ll1Prev.v[1], ll1.v[0], ll1.v[1], thr2, w2a);
      const float ll21 = haar1pair(ll1Prev.v[2], ll1Prev.v[3], ll1.v[2], ll1.v[3], thr2, w2a);
      if (p == 1) {
        ll2Prev0 = ll20; ll2Prev1 = ll21;
      } else {
        const float lh = (ll2Prev0 - ll2Prev1 + ll20 - ll21) * 0.5f;
        const float hl = (ll2Prev0 + ll2Prev1 - ll20 - ll21) * 0.5f;
        const float hh = (ll2Prev0 - ll2Prev1 - ll20 + ll21) * 0.5f;
        w3a += fminf(fabsf(lh), THR) + fminf(fabsf(hl), THR) + fminf(fabsf(hh), THR);
      }
    }

    g1m = g1p; g1c = g1q;
  }

  // ---- Wave reduce -> one pre-weighted double per wave, plain store ----
  float vals[5] = {rec, rgg, w1a, w2a, w3a};
#pragma unroll
  for (int v = 0; v < 5; ++v) {
#pragma unroll
    for (int off = 32; off > 0; off >>= 1) vals[v] += __shfl_down(vals[v], off);
  }
  if (lane == 0) {
    partial[gwid] = C_REC*(double)vals[0] + C_REG*(double)vals[1]
                  + C_W1*(double)vals[2] + C_W2*(double)vals[3] + C_W3*(double)vals[4];
  }
}

__global__ __launch_bounds__(256) void finalize_kernel(
    const double* __restrict__ partial, float* __restrict__ out) {
  __shared__ double sRed[4];
  const int t = threadIdx.x;
  double s = 0.0;
#pragma unroll
  for (int i = 0; i < NWAVES / 256; ++i) s += partial[i * 256 + t];
#pragma unroll
  for (int off = 32; off > 0; off >>= 1) s += __shfl_down(s, off);
  if ((t & 63) == 0) sRed[t >> 6] = s;
  __syncthreads();
  if (t == 0) out[0] = (float)(sRed[0] + sRed[1] + sRed[2] + sRed[3]);
}

}  // namespace

extern "C" void kernel_launch(void* const* d_in, const int* in_sizes, int n_in,
                              void* d_out, int out_size, void* d_ws, size_t ws_size,
                              hipStream_t stream) {
  const float* noisy  = (const float*)d_in[0];
  const float* weight = (const float*)d_in[1];
  double* partial = (double*)d_ws;   // NWAVES doubles = 16 KB
  float* out = (float*)d_out;

  hipLaunchKernelGGL(n2n_wavelet_kernel, dim3(NBLK), dim3(256), 0, stream,
                     noisy, weight, partial);
  hipLaunchKernelGGL(finalize_kernel, dim3(1), dim3(256), 0, stream, partial, out);
}